// Round 9
// baseline (2115.842 us; speedup 1.0000x reference)
//
#include <hip/hip_runtime.h>

// ============================================================================
// TypeNet triplet embedder: 2x(LSTM + BatchNorm) + FC + L2norm, for a,p,n.
// Round 13: R12 with the launch-bounds bug fixed.
//  R12 failed because __launch_bounds__(1024,4) capped VGPR at 64 -> all 32
//  weight frags spilled to scratch (WRITE_SIZE 480->22560 KB, lstm2 1536us).
//  The 2-tiles/WG occupancy idea was never tested. Fix: (1024,1) — one
//  16-wave block/CU needs VGPR<=128 and R8's code uses 124. No spills.
//  - lstm1/lstm2: 48 WGs x 1024 threads. Waves 0-7 run tile 2wg, waves 8-15
//    run tile 2wg+1 — R8 step-loop verbatim per tile, separate LDS h
//    double-buffers, one shared barrier (symmetric work). 4 waves/SIMD:
//    tile B's waves issue while tile A's sit in post-barrier LDS latency /
//    trans latency / barrier skew.
//  - prep_all / mid / head byte-identical to measured R8 (337us base).
// ============================================================================

typedef __attribute__((ext_vector_type(8))) _Float16 half8;
typedef __attribute__((ext_vector_type(4))) float f32x4;

#define TS 128
#define HID 128
#define NGATE 512
#define INV_N (1.0f/65536.0f)   // 1/(B*T)
#define NL2E  -1.4426950408889634f   // -log2(e)
#define N2L2E -2.8853900817779268f   // -2*log2(e)
#define GCLAMP 57.707801635558536f   // 20 * 2*log2(e)

#define BAR() asm volatile("s_waitcnt lgkmcnt(0)\n\ts_barrier" ::: "memory")

__device__ __forceinline__ float rcpf(float x) { return __builtin_amdgcn_rcpf(x); }
__device__ __forceinline__ float ex2(float x) { return __builtin_amdgcn_exp2f(x); }

// Gate pre-activations arrive PRE-SCALED: zi,zf,zo = -log2e*z, zg = -2log2e*z.
// 5 exp2 + 2 rcp per cell (merged f/ig denominator). R8-proven.
__device__ __forceinline__ float lstm_cell(float zi, float zf, float zg, float zo,
                                           float& c) {
  float zgc = __builtin_amdgcn_fmed3f(zg, -GCLAMP, GCLAMP);
  float ei = ex2(zi);
  float ef = ex2(zf);
  float eg = ex2(zgc);
  float eo = ex2(zo);
  float pi = 1.0f + ei, pg = 1.0f + eg, pf = 1.0f + ef;
  float P = pi * pg;
  float rd = rcpf(P * pf);
  float fv = P * rd;                    // sigmoid(zf)
  float ig = (1.0f - eg) * (pf * rd);   // sigmoid(zi)*tanh(zg)
  float cc = fv * c + ig;
  c = cc;
  float t2 = __builtin_amdgcn_fmed3f(cc * N2L2E, -GCLAMP, GCLAMP);
  float ec = ex2(t2);
  float hv = (1.0f - ec) * rcpf((1.0f + eo) * (1.0f + ec));  // sigmoid(zo)*tanh(cc)
  return hv;
}

// A-frag LDS/global layout for a 16x128 fp16 tile:
//   addr(row, col) = (col>>5)*512 + ((col>>3)&3)*128 + row*8 + (col&7)
// Reader (MFMA A-frag, row=l15, k=kt*32+quad*8+j): base = kt*512+(quad*16+l15)*8
// Weight (B-frag) layout: w[(kq*512 + g)*8 + j] = W^T[(kq>>2)*32+(kq&3)*8+j][g],
// gate-scaled by -log2e (-2log2e for gate g) so the cell uses raw exp2.

// ---------------------------------------------------------------------------
// Fused prep: xpad (A-frag fp16 x), B-frag scaled WhhT both layers, bias1.
// ---------------------------------------------------------------------------
__global__ void prep_all(const float* __restrict__ xa, const float* __restrict__ xp,
                         const float* __restrict__ xn,
                         const float* __restrict__ Whh1, const float* __restrict__ Whh2,
                         const float* __restrict__ bih1, const float* __restrict__ bhh1,
                         _Float16* __restrict__ xpad,
                         _Float16* __restrict__ whhT1, _Float16* __restrict__ whhT2,
                         float* __restrict__ b1c) {
  int bid = blockIdx.x, tid = threadIdx.x;
  if (bid < 768) {                       // xpad: one half8 per (tile,t,r)
    int i = bid * 256 + tid;             // [0, 196608)
    int tile = i >> 11, rem = i & 2047;
    int t = rem >> 4, r = rem & 15;
    int inp = tile >> 5, rloc = (tile & 31) * 16;
    const float* x = (inp == 0) ? xa : ((inp == 1) ? xp : xn);
    const float* row = x + (size_t)(rloc + r) * 640 + t * 5;
    half8 v = {0, 0, 0, 0, 0, 0, 0, 0};
#pragma unroll
    for (int j = 0; j < 5; ++j) v[j] = (_Float16)row[j];
    *(half8*)&xpad[(size_t)i * 8] = v;
  } else if (bid < 832) {                // whhT1/2: B-frag order, gate-scaled
    int i = (bid - 768) * 256 + tid;     // [0, 16384)
    int which = i >> 13, i8 = i & 8191;
    int kq = i8 >> 9, g = i8 & 511;
    int k0 = (kq >> 2) * 32 + (kq & 3) * 8;
    float gs = ((g >> 7) == 2) ? N2L2E : NL2E;
    const float* src = which ? Whh2 : Whh1;
    half8 v;
#pragma unroll
    for (int j = 0; j < 8; ++j) v[j] = (_Float16)(src[(size_t)g * HID + k0 + j] * gs);
    *(half8*)&(which ? whhT2 : whhT1)[(size_t)i8 * 8] = v;
  } else {                               // b1c (gate-scaled combined bias)
    int i = (bid - 832) * 256 + tid;     // [0, 512)
    float gs = ((i >> 7) == 2) ? N2L2E : NL2E;
    b1c[i] = (bih1[i] + bhh1[i]) * gs;
  }
}

// ---------------------------------------------------------------------------
// LSTM layer 1. 48 WGs x 1024 (2 tiles/WG). hs1: [96][128][2048] A-frag order.
// ---------------------------------------------------------------------------
__global__ __launch_bounds__(1024, 1) void lstm1_kernel(
    const _Float16* __restrict__ xpad,   // [96][128][16][8]
    const float* __restrict__ Wih1,      // [512][5]
    const float* __restrict__ b1c,       // [512] scaled
    const _Float16* __restrict__ whhT,   // [16 kq][512 g][8] B-frag, scaled
    _Float16* __restrict__ hs1,
    float* __restrict__ s1sum, float* __restrict__ s1sq) {
  const int wg = blockIdx.x;             // 0..47
  const int tid = threadIdx.x;           // 0..1023
  const int grp = tid >> 9;              // tile-group 0/1
  const int tix = tid & 511;
  const int tile = wg * 2 + grp;         // 0..95
  const int inp = tile >> 5;
  const int w = tix >> 6;                // 0..7
  const int lane = tid & 63;
  const int l15 = lane & 15;
  const int quad = lane >> 4;
  const int col = w * 16 + l15;

  __shared__ _Float16 hb[2][2][2048];    // [grp][dbuf][A-frag], 16 KB
  for (int i = tid; i < 8192; i += 1024) ((_Float16*)hb)[i] = (_Float16)0.0f;

  const int rbase = (quad * 16 + l15) * 8;
  const int wbase = (w >> 1) * 512 + ((w & 1) * 2 + (l15 >> 3)) * 128 +
                    quad * 32 + (l15 & 7);

  half8 bh[4][4];                        // [kt][gate], coalesced half8 loads
#pragma unroll
  for (int kt = 0; kt < 4; ++kt)
#pragma unroll
    for (int gt = 0; gt < 4; ++gt)
      bh[kt][gt] = *(const half8*)&whhT[(size_t)((kt * 4 + quad) * 512 + gt * 128 + col) * 8];

  half8 bx[4];                           // Wih1, gate-scaled, K=32-padded
#pragma unroll
  for (int gt = 0; gt < 4; ++gt) {
    half8 v = {0, 0, 0, 0, 0, 0, 0, 0};
    if (quad == 0) {
      float gs = (gt == 2) ? N2L2E : NL2E;
#pragma unroll
      for (int j = 0; j < 5; ++j) v[j] = (_Float16)(Wih1[(gt * 128 + col) * 5 + j] * gs);
    }
    bx[gt] = v;
  }
  f32x4 biasv[4];
#pragma unroll
  for (int gt = 0; gt < 4; ++gt) {
    float b = b1c[gt * 128 + col];
    biasv[gt][0] = b; biasv[gt][1] = b; biasv[gt][2] = b; biasv[gt][3] = b;
  }

  half8 xp = {0, 0, 0, 0, 0, 0, 0, 0};
  if (quad == 0) xp = *(const half8*)&xpad[((size_t)(tile * TS) * 16 + l15) * 8];

  float c[4] = {0, 0, 0, 0};
  float ssum = 0.0f, ssq = 0.0f;
  _Float16* hs1w = hs1 + (size_t)tile * TS * 2048;

  for (int t = 0; t < TS; ++t) {
    BAR();                               // h(t-1) (and t=0 zero-init) visible
    half8 ah[4];                         // issue LDS reads first...
#pragma unroll
    for (int kt = 0; kt < 4; ++kt)
      ah[kt] = *(const half8*)&hb[grp][t & 1][kt * 512 + rbase];
    if (t > 0) {                         // coalesced h(t-1) -> hs1 (8 B/thread)
      float2 cp = *(const float2*)&hb[grp][t & 1][tix * 4];
      *(float2*)&hs1w[(size_t)(t - 1) * 2048 + tix * 4] = cp;
    }
    f32x4 acc[4];                        // ...x-part MFMAs hide LDS latency
#pragma unroll
    for (int gt = 0; gt < 4; ++gt)
      acc[gt] = __builtin_amdgcn_mfma_f32_16x16x32_f16(xp, bx[gt], biasv[gt], 0, 0, 0);
    if (t + 1 < TS && quad == 0)
      xp = *(const half8*)&xpad[((size_t)(tile * TS + t + 1) * 16 + l15) * 8];
#pragma unroll
    for (int kt = 0; kt < 4; ++kt)
#pragma unroll
      for (int gt = 0; gt < 4; ++gt)
        acc[gt] = __builtin_amdgcn_mfma_f32_16x16x32_f16(ah[kt], bh[kt][gt], acc[gt], 0, 0, 0);
    const int wb = (t + 1) & 1;
    float hv4[4];
#pragma unroll
    for (int r = 0; r < 4; ++r) {
      float hv = lstm_cell(acc[0][r], acc[1][r], acc[2][r], acc[3][r], c[r]);
      hb[grp][wb][wbase + r * 8] = (_Float16)hv;
      hv4[r] = hv;
    }
#pragma unroll
    for (int r = 0; r < 4; ++r) { ssum += hv4[r]; ssq += hv4[r] * hv4[r]; }
  }
  BAR();                                 // h(127) visible
  {
    float2 cp = *(const float2*)&hb[grp][0][tix * 4];
    *(float2*)&hs1w[(size_t)(TS - 1) * 2048 + tix * 4] = cp;
  }
  float s = ssum, q = ssq;
  s += __shfl_xor(s, 16); s += __shfl_xor(s, 32);
  q += __shfl_xor(q, 16); q += __shfl_xor(q, 32);
  if (quad == 0) {
    atomicAdd(&s1sum[inp * HID + col], s);
    atomicAdd(&s1sq[inp * HID + col], q);
  }
}

// ---------------------------------------------------------------------------
// Mid: BN1-folded scaled W2 (fp16, B-frag order) + effective bias2.
// ---------------------------------------------------------------------------
__global__ void mid_kernel(const float* __restrict__ s1sum, const float* __restrict__ s1sq,
                           const float* __restrict__ g1, const float* __restrict__ b1,
                           const float* __restrict__ Wih2,
                           const float* __restrict__ bih2, const float* __restrict__ bhh2,
                           _Float16* __restrict__ w2s, float* __restrict__ bias2eff) {
  int bid = blockIdx.x, tid = threadIdx.x;
  __shared__ float scB[8];
  __shared__ float shL[128];
  if (bid < 96) {                        // w2s: [3][16 kq][512 g][8] B-frag
    int i = bid * 256 + tid;             // [0, 24576)
    int inp = i >> 13, i8 = i & 8191;    // kq uniform per block
    int kq = i8 >> 9, g = i8 & 511;
    int k0 = (kq >> 2) * 32 + (kq & 3) * 8;
    if (tid < 8) {
      int k = k0 + tid;
      float m = s1sum[inp * HID + k] * INV_N;
      float v = s1sq[inp * HID + k] * INV_N - m * m;
      scB[tid] = g1[k] * rsqrtf(v + 1e-5f);
    }
    __syncthreads();
    float gs = ((g >> 7) == 2) ? N2L2E : NL2E;
    const float* wr = Wih2 + (size_t)g * HID + k0;
    half8 v;
#pragma unroll
    for (int j = 0; j < 8; ++j) v[j] = (_Float16)(scB[j] * wr[j] * gs);
    *(half8*)&w2s[((size_t)inp * 8192 + i8) * 8] = v;
  } else {                               // bias2eff: [3][512], gate-scaled
    int i = (bid - 96) * 256 + tid;      // [0, 1536); inp uniform per block
    int inp = i >> 9, g = i & 511;
    if (tid < 128) {
      float m = s1sum[inp * HID + tid] * INV_N;
      float v = s1sq[inp * HID + tid] * INV_N - m * m;
      float s = g1[tid] * rsqrtf(v + 1e-5f);
      shL[tid] = b1[tid] - m * s;
    }
    __syncthreads();
    float acc = bih2[g] + bhh2[g];
    for (int h = 0; h < HID; ++h) acc += shL[h] * Wih2[(size_t)g * HID + h];
    float gs = ((g >> 7) == 2) ? N2L2E : NL2E;
    bias2eff[i] = acc * gs;
  }
}

// ---------------------------------------------------------------------------
// LSTM layer 2. 48 WGs x 1024 (2 tiles/WG): folded-BN1 input GEMM + recurrence.
// ---------------------------------------------------------------------------
__global__ __launch_bounds__(1024, 1) void lstm2_kernel(
    const _Float16* __restrict__ hs1,    // [96][128][2048] A-frag order
    const _Float16* __restrict__ whhT2,  // [16 kq][512 g][8] B-frag, scaled
    const _Float16* __restrict__ w2s,    // [3][16 kq][512 g][8] B-frag, scaled
    const float* __restrict__ bias2eff,  // [3][512] scaled
    _Float16* __restrict__ h_last,       // [1536][128]
    float* __restrict__ s2sum, float* __restrict__ s2sq) {
  const int wg = blockIdx.x;             // 0..47
  const int tid = threadIdx.x;           // 0..1023
  const int grp = tid >> 9;              // tile-group 0/1
  const int tix = tid & 511;
  const int tile = wg * 2 + grp;         // 0..95
  const int inp = tile >> 5;
  const int gr0 = tile * 16;
  const int w = tix >> 6;
  const int lane = tid & 63;
  const int l15 = lane & 15;
  const int quad = lane >> 4;
  const int col = w * 16 + l15;

  __shared__ _Float16 hb[2][2][2048];    // [grp][dbuf][A-frag], 16 KB
  for (int i = tid; i < 8192; i += 1024) ((_Float16*)hb)[i] = (_Float16)0.0f;

  const int rbase = (quad * 16 + l15) * 8;
  const int wbase = (w >> 1) * 512 + ((w & 1) * 2 + (l15 >> 3)) * 128 +
                    quad * 32 + (l15 & 7);

  const _Float16* w2sI = w2s + (size_t)inp * HID * NGATE;
  half8 bh[4][4], bxw[4][4];
#pragma unroll
  for (int kt = 0; kt < 4; ++kt)
#pragma unroll
    for (int gt = 0; gt < 4; ++gt) {
      size_t gi = (size_t)((kt * 4 + quad) * 512 + gt * 128 + col) * 8;
      bh[kt][gt] = *(const half8*)&whhT2[gi];
      bxw[kt][gt] = *(const half8*)&w2sI[gi];
    }
  f32x4 biasv[4];
#pragma unroll
  for (int gt = 0; gt < 4; ++gt) {
    float b = bias2eff[inp * NGATE + gt * 128 + col];
    biasv[gt][0] = b; biasv[gt][1] = b; biasv[gt][2] = b; biasv[gt][3] = b;
  }

  const _Float16* hg = hs1 + (size_t)tile * TS * 2048;
  half8 a2A[4], a2B[4];                  // 2-deep prefetch (coalesced 16B loads)
#pragma unroll
  for (int kt = 0; kt < 4; ++kt) {
    a2A[kt] = *(const half8*)&hg[kt * 512 + rbase];
    a2B[kt] = *(const half8*)&hg[(size_t)2048 + kt * 512 + rbase];
  }

  float c[4] = {0, 0, 0, 0};
  float ssum = 0.0f, ssq = 0.0f;

  auto step = [&](int t, half8 (&cur)[4]) {
    BAR();                               // h(t-1) visible; vmcnt untouched
    half8 ah[4];                         // issue LDS reads first...
#pragma unroll
    for (int kt = 0; kt < 4; ++kt)
      ah[kt] = *(const half8*)&hb[grp][t & 1][kt * 512 + rbase];
    f32x4 acc[4];                        // ...x-part MFMAs hide LDS latency
#pragma unroll
    for (int gt = 0; gt < 4; ++gt)
      acc[gt] = __builtin_amdgcn_mfma_f32_16x16x32_f16(cur[0], bxw[0][gt], biasv[gt], 0, 0, 0);
#pragma unroll
    for (int kt = 1; kt < 4; ++kt)
#pragma unroll
      for (int gt = 0; gt < 4; ++gt)
        acc[gt] = __builtin_amdgcn_mfma_f32_16x16x32_f16(cur[kt], bxw[kt][gt], acc[gt], 0, 0, 0);
    if (t + 2 < TS) {                    // prefetch t+2 into regs just consumed
#pragma unroll
      for (int kt = 0; kt < 4; ++kt)
        cur[kt] = *(const half8*)&hg[(size_t)(t + 2) * 2048 + kt * 512 + rbase];
    }
#pragma unroll
    for (int kt = 0; kt < 4; ++kt)
#pragma unroll
      for (int gt = 0; gt < 4; ++gt)
        acc[gt] = __builtin_amdgcn_mfma_f32_16x16x32_f16(ah[kt], bh[kt][gt], acc[gt], 0, 0, 0);
    const int wb = (t + 1) & 1;
    float hv4[4];
#pragma unroll
    for (int r = 0; r < 4; ++r) {
      float hv = lstm_cell(acc[0][r], acc[1][r], acc[2][r], acc[3][r], c[r]);
      _Float16 hh = (_Float16)hv;
      hb[grp][wb][wbase + r * 8] = hh;
      hv4[r] = hv;
      if (t == TS - 1) h_last[(size_t)(gr0 + quad * 4 + r) * HID + col] = hh;
    }
#pragma unroll
    for (int r = 0; r < 4; ++r) { ssum += hv4[r]; ssq += hv4[r] * hv4[r]; }
  };

  for (int t = 0; t < TS; t += 2) {
    step(t, a2A);
    step(t + 1, a2B);
  }

  float s = ssum, q = ssq;
  s += __shfl_xor(s, 16); s += __shfl_xor(s, 32);
  q += __shfl_xor(q, 16); q += __shfl_xor(q, 32);
  if (quad == 0) {
    atomicAdd(&s2sum[inp * HID + col], s);
    atomicAdd(&s2sq[inp * HID + col], q);
  }
}

// ---------------------------------------------------------------------------
// Head: BN2 finalize + FC + L2 normalize. 96 WGs x 16 rows.
// ---------------------------------------------------------------------------
__global__ __launch_bounds__(256, 1) void head_kernel(
    const _Float16* __restrict__ h_last,
    const float* __restrict__ s2sum, const float* __restrict__ s2sq,
    const float* __restrict__ g2, const float* __restrict__ b2,
    const float* __restrict__ fcW, const float* __restrict__ fcb,
    float* __restrict__ out) {
  const int wg = blockIdx.x;
  const int inp = wg >> 5;
  const int gr0 = wg * 16;
  const int tid = threadIdx.x;

  __shared__ float fcwT[128][132];       // fcwT[h][j] = fcW[j][h]
  __shared__ float bnh[16][132];
  __shared__ float s2[128], sh2[128];
  __shared__ float part[16][16];
  __shared__ float inv[16];

  if (tid < 128) {
    float m = s2sum[inp * HID + tid] * INV_N;
    float v = s2sq[inp * HID + tid] * INV_N - m * m;
    float s = g2[tid] * rsqrtf(v + 1e-5f);
    s2[tid] = s; sh2[tid] = b2[tid] - m * s;
  }
  for (int i = tid; i < 16384; i += 256) {
    int j = i >> 7, h = i & 127;
    fcwT[h][j] = fcW[i];
  }
  __syncthreads();
  {
    int row = tid >> 4, c0 = (tid & 15) * 8;
#pragma unroll
    for (int k = 0; k < 8; ++k) {
      int h = c0 + k;
      bnh[row][h] = (float)h_last[(gr0 + row) * HID + h] * s2[h] + sh2[h];
    }
  }
  __syncthreads();
  const int row = tid >> 4, jl = tid & 15;
  float emb[8];
  float sq = 0.0f;
#pragma unroll
  for (int jj = 0; jj < 8; ++jj) {
    int j = jl + jj * 16;
    float acc = fcb[j];
    for (int h = 0; h < HID; ++h) acc += bnh[row][h] * fcwT[h][j];
    emb[jj] = acc; sq += acc * acc;
  }
  part[row][jl] = sq;
  __syncthreads();
  if (tid < 16) {
    float s = 0.0f;
    for (int k = 0; k < 16; ++k) s += part[tid][k];
    float nrm = sqrtf(s);
    inv[tid] = 1.0f / fmaxf(nrm, 1e-12f);
  }
  __syncthreads();
#pragma unroll
  for (int jj = 0; jj < 8; ++jj)
    out[(gr0 + row) * HID + jl + jj * 16] = emb[jj] * inv[row];
}

// ---------------------------------------------------------------------------
extern "C" void kernel_launch(void* const* d_in, const int* in_sizes, int n_in,
                              void* d_out, int out_size, void* d_ws, size_t ws_size,
                              hipStream_t stream) {
  const float* a    = (const float*)d_in[0];
  const float* p    = (const float*)d_in[1];
  const float* nn   = (const float*)d_in[2];
  const float* Wih1 = (const float*)d_in[3];
  const float* Whh1 = (const float*)d_in[4];
  const float* bih1 = (const float*)d_in[5];
  const float* bhh1 = (const float*)d_in[6];
  const float* g1   = (const float*)d_in[7];
  const float* b1   = (const float*)d_in[8];
  const float* Wih2 = (const float*)d_in[9];
  const float* Whh2 = (const float*)d_in[10];
  const float* bih2 = (const float*)d_in[11];
  const float* bhh2 = (const float*)d_in[12];
  const float* g2   = (const float*)d_in[13];
  const float* b2   = (const float*)d_in[14];
  const float* fcW  = (const float*)d_in[15];
  const float* fcb  = (const float*)d_in[16];

  char* ws = (char*)d_ws;
  float* s1sum = (float*)(ws + 0);            // 384 f32
  float* s1sq  = s1sum + 384;
  float* s2sum = s1sum + 768;
  float* s2sq  = s1sum + 1152;                // stats end @6144B
  float* b1c      = (float*)(ws + 6144);      // 512 f32 -> @8192
  float* bias2eff = (float*)(ws + 8192);      // 1536 f32 -> @14336
  _Float16* whhT1 = (_Float16*)(ws + 14336);    // 131072B -> @145408
  _Float16* whhT2 = (_Float16*)(ws + 145408);   // 131072B -> @276480
  _Float16* w2s   = (_Float16*)(ws + 276480);   // 393216B -> @669696
  _Float16* hlast = (_Float16*)(ws + 669696);   // 393216B -> @1062912
  _Float16* xpad  = (_Float16*)(ws + 1062912);  // 3145728B -> @4208640
  _Float16* hs1   = (_Float16*)(ws + 4208640);  // 50331648B -> ~54.5MB total

  hipMemsetAsync(ws, 0, 6144, stream);  // zero BN stats accumulators

  prep_all<<<834, 256, 0, stream>>>(a, p, nn, Whh1, Whh2, bih1, bhh1,
                                    xpad, whhT1, whhT2, b1c);
  lstm1_kernel<<<48, 1024, 0, stream>>>(xpad, Wih1, b1c, whhT1, hs1, s1sum, s1sq);
  mid_kernel<<<102, 256, 0, stream>>>(s1sum, s1sq, g1, b1, Wih2, bih2, bhh2,
                                      w2s, bias2eff);
  lstm2_kernel<<<48, 1024, 0, stream>>>(hs1, whhT2, w2s, bias2eff, hlast, s2sum, s2sq);
  head_kernel<<<96, 256, 0, stream>>>(hlast, s2sum, s2sq, g2, b2, fcW, fcb, (float*)d_out);
}

// Round 11
// 434.776 us; speedup vs baseline: 4.8665x; 4.8665x over previous
//
#include <hip/hip_runtime.h>

// ============================================================================
// TypeNet triplet embedder: 2x(LSTM + BatchNorm) + FC + L2norm, for a,p,n.
// Round 14 (resubmit — R10 bench was GPUAcquisitionTimeout, no data):
// R8 base (337us measured); lstm1 -> dual-recurrence PER WAVE.
//  - R12/R13 audit: 2-tiles-per-WG is register-infeasible (per-thread state
//    ~200 regs vs 128 cap at 4 waves/SIMD) — abandoned.
//  - lstm1: 48 WGs x 512; each WAVE runs tiles 2wg and 2wg+1 simultaneously
//    in the same phase: 8 independent MFMA chains + 8 independent cell chains
//    interleaved in program order, ONE barrier/step. Chain-B ops issue while
//    chain-A sits in exp2/MFMA latency (ILP x2). Weights/bias regs shared.
//    ~215 VGPR < 256 cap (launch_bounds(512,2)) — no spill expected.
//    Worst case (no interleave) = per-tile time unchanged -> neutral.
//  - lstm2 / mid / head byte-identical to measured R8 (register-infeasible
//    to dualize: +bxw pushes ~300 regs).
//  - prep_all: stats zeroing folded in (memset dispatch removed).
// ============================================================================

typedef __attribute__((ext_vector_type(8))) _Float16 half8;
typedef __attribute__((ext_vector_type(4))) float f32x4;

#define TS 128
#define HID 128
#define NGATE 512
#define INV_N (1.0f/65536.0f)   // 1/(B*T)
#define NL2E  -1.4426950408889634f   // -log2(e)
#define N2L2E -2.8853900817779268f   // -2*log2(e)
#define GCLAMP 57.707801635558536f   // 20 * 2*log2(e)

#define BAR() asm volatile("s_waitcnt lgkmcnt(0)\n\ts_barrier" ::: "memory")

__device__ __forceinline__ float rcpf(float x) { return __builtin_amdgcn_rcpf(x); }
__device__ __forceinline__ float ex2(float x) { return __builtin_amdgcn_exp2f(x); }

// Gate pre-activations arrive PRE-SCALED: zi,zf,zo = -log2e*z, zg = -2log2e*z.
// 5 exp2 + 2 rcp per cell (merged f/ig denominator). R8-proven.
__device__ __forceinline__ float lstm_cell(float zi, float zf, float zg, float zo,
                                           float& c) {
  float zgc = __builtin_amdgcn_fmed3f(zg, -GCLAMP, GCLAMP);
  float ei = ex2(zi);
  float ef = ex2(zf);
  float eg = ex2(zgc);
  float eo = ex2(zo);
  float pi = 1.0f + ei, pg = 1.0f + eg, pf = 1.0f + ef;
  float P = pi * pg;
  float rd = rcpf(P * pf);
  float fv = P * rd;                    // sigmoid(zf)
  float ig = (1.0f - eg) * (pf * rd);   // sigmoid(zi)*tanh(zg)
  float cc = fv * c + ig;
  c = cc;
  float t2 = __builtin_amdgcn_fmed3f(cc * N2L2E, -GCLAMP, GCLAMP);
  float ec = ex2(t2);
  float hv = (1.0f - ec) * rcpf((1.0f + eo) * (1.0f + ec));  // sigmoid(zo)*tanh(cc)
  return hv;
}

// A-frag LDS/global layout for a 16x128 fp16 tile:
//   addr(row, col) = (col>>5)*512 + ((col>>3)&3)*128 + row*8 + (col&7)
// Reader (MFMA A-frag, row=l15, k=kt*32+quad*8+j): base = kt*512+(quad*16+l15)*8
// Weight (B-frag) layout: w[(kq*512 + g)*8 + j] = W^T[(kq>>2)*32+(kq&3)*8+j][g],
// gate-scaled by -log2e (-2log2e for gate g) so the cell uses raw exp2.

// ---------------------------------------------------------------------------
// Fused prep: xpad (A-frag fp16 x), B-frag scaled WhhT both layers, bias1,
// and BN-stats zeroing (replaces the hipMemsetAsync dispatch).
// ---------------------------------------------------------------------------
__global__ void prep_all(const float* __restrict__ xa, const float* __restrict__ xp,
                         const float* __restrict__ xn,
                         const float* __restrict__ Whh1, const float* __restrict__ Whh2,
                         const float* __restrict__ bih1, const float* __restrict__ bhh1,
                         _Float16* __restrict__ xpad,
                         _Float16* __restrict__ whhT1, _Float16* __restrict__ whhT2,
                         float* __restrict__ b1c, float* __restrict__ stats) {
  int bid = blockIdx.x, tid = threadIdx.x;
  if (bid < 768) {                       // xpad: one half8 per (tile,t,r)
    int i = bid * 256 + tid;             // [0, 196608)
    int tile = i >> 11, rem = i & 2047;
    int t = rem >> 4, r = rem & 15;
    int inp = tile >> 5, rloc = (tile & 31) * 16;
    const float* x = (inp == 0) ? xa : ((inp == 1) ? xp : xn);
    const float* row = x + (size_t)(rloc + r) * 640 + t * 5;
    half8 v = {0, 0, 0, 0, 0, 0, 0, 0};
#pragma unroll
    for (int j = 0; j < 5; ++j) v[j] = (_Float16)row[j];
    *(half8*)&xpad[(size_t)i * 8] = v;
  } else if (bid < 832) {                // whhT1/2: B-frag order, gate-scaled
    int i = (bid - 768) * 256 + tid;     // [0, 16384)
    int which = i >> 13, i8 = i & 8191;
    int kq = i8 >> 9, g = i8 & 511;
    int k0 = (kq >> 2) * 32 + (kq & 3) * 8;
    float gs = ((g >> 7) == 2) ? N2L2E : NL2E;
    const float* src = which ? Whh2 : Whh1;
    half8 v;
#pragma unroll
    for (int j = 0; j < 8; ++j) v[j] = (_Float16)(src[(size_t)g * HID + k0 + j] * gs);
    *(half8*)&(which ? whhT2 : whhT1)[(size_t)i8 * 8] = v;
  } else if (bid < 834) {                // b1c (gate-scaled combined bias)
    int i = (bid - 832) * 256 + tid;     // [0, 512)
    float gs = ((i >> 7) == 2) ? N2L2E : NL2E;
    b1c[i] = (bih1[i] + bhh1[i]) * gs;
  } else {                               // zero BN stats (1536 f32)
#pragma unroll
    for (int j = 0; j < 6; ++j) stats[tid * 6 + j] = 0.0f;
  }
}

// ---------------------------------------------------------------------------
// LSTM layer 1, dual-recurrence per wave. 48 WGs x 512; each wave runs tiles
// 2wg (A) and 2wg+1 (B) in the same phase — 8 independent MFMA/cell chains
// interleave to fill latency stalls. hs1: [96][128][2048] A-frag order.
// ---------------------------------------------------------------------------
__global__ __launch_bounds__(512, 2) void lstm1_kernel(
    const _Float16* __restrict__ xpad,   // [96][128][16][8]
    const float* __restrict__ Wih1,      // [512][5]
    const float* __restrict__ b1c,       // [512] scaled
    const _Float16* __restrict__ whhT,   // [16 kq][512 g][8] B-frag, scaled
    _Float16* __restrict__ hs1,
    float* __restrict__ s1sum, float* __restrict__ s1sq) {
  const int wg = blockIdx.x;             // 0..47
  const int tA = wg * 2, tB = tA + 1;    // the two tiles (same inp)
  const int inp = tA >> 5;
  const int tid = threadIdx.x;
  const int w = tid >> 6;                // 0..7
  const int lane = tid & 63;
  const int l15 = lane & 15;
  const int quad = lane >> 4;
  const int col = w * 16 + l15;

  __shared__ _Float16 hb[2][2][2048];    // [tile][dbuf][A-frag], 16 KB
  for (int i = tid; i < 8192; i += 512) ((_Float16*)hb)[i] = (_Float16)0.0f;

  const int rbase = (quad * 16 + l15) * 8;
  const int wbase = (w >> 1) * 512 + ((w & 1) * 2 + (l15 >> 3)) * 128 +
                    quad * 32 + (l15 & 7);

  half8 bh[4][4];                        // [kt][gate] — SHARED by both tiles
#pragma unroll
  for (int kt = 0; kt < 4; ++kt)
#pragma unroll
    for (int gt = 0; gt < 4; ++gt)
      bh[kt][gt] = *(const half8*)&whhT[(size_t)((kt * 4 + quad) * 512 + gt * 128 + col) * 8];

  half8 bx[4];                           // Wih1, gate-scaled, K=32-padded
#pragma unroll
  for (int gt = 0; gt < 4; ++gt) {
    half8 v = {0, 0, 0, 0, 0, 0, 0, 0};
    if (quad == 0) {
      float gs = (gt == 2) ? N2L2E : NL2E;
#pragma unroll
      for (int j = 0; j < 5; ++j) v[j] = (_Float16)(Wih1[(gt * 128 + col) * 5 + j] * gs);
    }
    bx[gt] = v;
  }
  f32x4 biasv[4];
#pragma unroll
  for (int gt = 0; gt < 4; ++gt) {
    float b = b1c[gt * 128 + col];
    biasv[gt][0] = b; biasv[gt][1] = b; biasv[gt][2] = b; biasv[gt][3] = b;
  }

  half8 xpA = {0, 0, 0, 0, 0, 0, 0, 0};
  half8 xpB = {0, 0, 0, 0, 0, 0, 0, 0};
  if (quad == 0) {
    xpA = *(const half8*)&xpad[((size_t)(tA * TS) * 16 + l15) * 8];
    xpB = *(const half8*)&xpad[((size_t)(tB * TS) * 16 + l15) * 8];
  }

  float cA[4] = {0, 0, 0, 0}, cB[4] = {0, 0, 0, 0};
  float ssum = 0.0f, ssq = 0.0f;         // shared (both tiles same inp)
  _Float16* hsA = hs1 + (size_t)tA * TS * 2048;
  _Float16* hsB = hs1 + (size_t)tB * TS * 2048;

  for (int t = 0; t < TS; ++t) {
    BAR();                               // h(t-1) (and t=0 zero-init) visible
    half8 ahA[4], ahB[4];                // issue all LDS reads first
#pragma unroll
    for (int kt = 0; kt < 4; ++kt) {
      ahA[kt] = *(const half8*)&hb[0][t & 1][kt * 512 + rbase];
      ahB[kt] = *(const half8*)&hb[1][t & 1][kt * 512 + rbase];
    }
    if (t > 0) {                         // coalesced h(t-1) -> hs1 (8 B x2)
      float2 cpA = *(const float2*)&hb[0][t & 1][tid * 4];
      *(float2*)&hsA[(size_t)(t - 1) * 2048 + tid * 4] = cpA;
      float2 cpB = *(const float2*)&hb[1][t & 1][tid * 4];
      *(float2*)&hsB[(size_t)(t - 1) * 2048 + tid * 4] = cpB;
    }
    f32x4 accA[4], accB[4];              // x-part MFMAs hide LDS latency
#pragma unroll
    for (int gt = 0; gt < 4; ++gt) {
      accA[gt] = __builtin_amdgcn_mfma_f32_16x16x32_f16(xpA, bx[gt], biasv[gt], 0, 0, 0);
      accB[gt] = __builtin_amdgcn_mfma_f32_16x16x32_f16(xpB, bx[gt], biasv[gt], 0, 0, 0);
    }
    if (t + 1 < TS && quad == 0) {
      xpA = *(const half8*)&xpad[((size_t)(tA * TS + t + 1) * 16 + l15) * 8];
      xpB = *(const half8*)&xpad[((size_t)(tB * TS + t + 1) * 16 + l15) * 8];
    }
#pragma unroll
    for (int kt = 0; kt < 4; ++kt)       // 8 independent h-MFMA chains
#pragma unroll
      for (int gt = 0; gt < 4; ++gt) {
        accA[gt] = __builtin_amdgcn_mfma_f32_16x16x32_f16(ahA[kt], bh[kt][gt], accA[gt], 0, 0, 0);
        accB[gt] = __builtin_amdgcn_mfma_f32_16x16x32_f16(ahB[kt], bh[kt][gt], accB[gt], 0, 0, 0);
      }
    const int wb = (t + 1) & 1;
#pragma unroll
    for (int r = 0; r < 4; ++r) {        // 8 independent cell chains interleave
      float hvA = lstm_cell(accA[0][r], accA[1][r], accA[2][r], accA[3][r], cA[r]);
      float hvB = lstm_cell(accB[0][r], accB[1][r], accB[2][r], accB[3][r], cB[r]);
      hb[0][wb][wbase + r * 8] = (_Float16)hvA;
      hb[1][wb][wbase + r * 8] = (_Float16)hvB;
      ssum += hvA + hvB;
      ssq += hvA * hvA + hvB * hvB;
    }
  }
  BAR();                                 // h(127) visible
  {
    float2 cpA = *(const float2*)&hb[0][0][tid * 4];
    *(float2*)&hsA[(size_t)(TS - 1) * 2048 + tid * 4] = cpA;
    float2 cpB = *(const float2*)&hb[1][0][tid * 4];
    *(float2*)&hsB[(size_t)(TS - 1) * 2048 + tid * 4] = cpB;
  }
  float s = ssum, q = ssq;
  s += __shfl_xor(s, 16); s += __shfl_xor(s, 32);
  q += __shfl_xor(q, 16); q += __shfl_xor(q, 32);
  if (quad == 0) {
    atomicAdd(&s1sum[inp * HID + col], s);
    atomicAdd(&s1sq[inp * HID + col], q);
  }
}

// ---------------------------------------------------------------------------
// Mid: BN1-folded scaled W2 (fp16, B-frag order) + effective bias2.
// ---------------------------------------------------------------------------
__global__ void mid_kernel(const float* __restrict__ s1sum, const float* __restrict__ s1sq,
                           const float* __restrict__ g1, const float* __restrict__ b1,
                           const float* __restrict__ Wih2,
                           const float* __restrict__ bih2, const float* __restrict__ bhh2,
                           _Float16* __restrict__ w2s, float* __restrict__ bias2eff) {
  int bid = blockIdx.x, tid = threadIdx.x;
  __shared__ float scB[8];
  __shared__ float shL[128];
  if (bid < 96) {                        // w2s: [3][16 kq][512 g][8] B-frag
    int i = bid * 256 + tid;             // [0, 24576)
    int inp = i >> 13, i8 = i & 8191;    // kq uniform per block
    int kq = i8 >> 9, g = i8 & 511;
    int k0 = (kq >> 2) * 32 + (kq & 3) * 8;
    if (tid < 8) {
      int k = k0 + tid;
      float m = s1sum[inp * HID + k] * INV_N;
      float v = s1sq[inp * HID + k] * INV_N - m * m;
      scB[tid] = g1[k] * rsqrtf(v + 1e-5f);
    }
    __syncthreads();
    float gs = ((g >> 7) == 2) ? N2L2E : NL2E;
    const float* wr = Wih2 + (size_t)g * HID + k0;
    half8 v;
#pragma unroll
    for (int j = 0; j < 8; ++j) v[j] = (_Float16)(scB[j] * wr[j] * gs);
    *(half8*)&w2s[((size_t)inp * 8192 + i8) * 8] = v;
  } else {                               // bias2eff: [3][512], gate-scaled
    int i = (bid - 96) * 256 + tid;      // [0, 1536); inp uniform per block
    int inp = i >> 9, g = i & 511;
    if (tid < 128) {
      float m = s1sum[inp * HID + tid] * INV_N;
      float v = s1sq[inp * HID + tid] * INV_N - m * m;
      float s = g1[tid] * rsqrtf(v + 1e-5f);
      shL[tid] = b1[tid] - m * s;
    }
    __syncthreads();
    float acc = bih2[g] + bhh2[g];
    for (int h = 0; h < HID; ++h) acc += shL[h] * Wih2[(size_t)g * HID + h];
    float gs = ((g >> 7) == 2) ? N2L2E : NL2E;
    bias2eff[i] = acc * gs;
  }
}

// ---------------------------------------------------------------------------
// LSTM layer 2: fused (folded-BN1) input GEMM + recurrence. 96 WGs x 512.
// Byte-identical to measured R8 (dual-per-wave infeasible: ~300 regs).
// ---------------------------------------------------------------------------
__global__ __launch_bounds__(512, 2) void lstm2_kernel(
    const _Float16* __restrict__ hs1,    // [96][128][2048] A-frag order
    const _Float16* __restrict__ whhT2,  // [16 kq][512 g][8] B-frag, scaled
    const _Float16* __restrict__ w2s,    // [3][16 kq][512 g][8] B-frag, scaled
    const float* __restrict__ bias2eff,  // [3][512] scaled
    _Float16* __restrict__ h_last,       // [1536][128]
    float* __restrict__ s2sum, float* __restrict__ s2sq) {
  const int wg = blockIdx.x;             // tile 0..95
  const int inp = wg >> 5;
  const int gr0 = wg * 16;
  const int tid = threadIdx.x;
  const int w = tid >> 6;
  const int lane = tid & 63;
  const int l15 = lane & 15;
  const int quad = lane >> 4;
  const int col = w * 16 + l15;

  __shared__ _Float16 hb[2][2048];
  for (int i = tid; i < 4096; i += 512) ((_Float16*)hb)[i] = (_Float16)0.0f;

  const int rbase = (quad * 16 + l15) * 8;
  const int wbase = (w >> 1) * 512 + ((w & 1) * 2 + (l15 >> 3)) * 128 +
                    quad * 32 + (l15 & 7);

  const _Float16* w2sI = w2s + (size_t)inp * HID * NGATE;
  half8 bh[4][4], bxw[4][4];
#pragma unroll
  for (int kt = 0; kt < 4; ++kt)
#pragma unroll
    for (int gt = 0; gt < 4; ++gt) {
      size_t gi = (size_t)((kt * 4 + quad) * 512 + gt * 128 + col) * 8;
      bh[kt][gt] = *(const half8*)&whhT2[gi];
      bxw[kt][gt] = *(const half8*)&w2sI[gi];
    }
  f32x4 biasv[4];
#pragma unroll
  for (int gt = 0; gt < 4; ++gt) {
    float b = bias2eff[inp * NGATE + gt * 128 + col];
    biasv[gt][0] = b; biasv[gt][1] = b; biasv[gt][2] = b; biasv[gt][3] = b;
  }

  const _Float16* hg = hs1 + (size_t)wg * TS * 2048;
  half8 a2A[4], a2B[4];                  // 2-deep prefetch (coalesced 16B loads)
#pragma unroll
  for (int kt = 0; kt < 4; ++kt) {
    a2A[kt] = *(const half8*)&hg[kt * 512 + rbase];
    a2B[kt] = *(const half8*)&hg[(size_t)2048 + kt * 512 + rbase];
  }

  float c[4] = {0, 0, 0, 0};
  float ssum = 0.0f, ssq = 0.0f;

  auto step = [&](int t, half8 (&cur)[4]) {
    BAR();                               // h(t-1) visible; vmcnt untouched
    half8 ah[4];                         // issue LDS reads first...
#pragma unroll
    for (int kt = 0; kt < 4; ++kt)
      ah[kt] = *(const half8*)&hb[t & 1][kt * 512 + rbase];
    f32x4 acc[4];                        // ...x-part MFMAs hide LDS latency
#pragma unroll
    for (int gt = 0; gt < 4; ++gt)
      acc[gt] = __builtin_amdgcn_mfma_f32_16x16x32_f16(cur[0], bxw[0][gt], biasv[gt], 0, 0, 0);
#pragma unroll
    for (int kt = 1; kt < 4; ++kt)
#pragma unroll
      for (int gt = 0; gt < 4; ++gt)
        acc[gt] = __builtin_amdgcn_mfma_f32_16x16x32_f16(cur[kt], bxw[kt][gt], acc[gt], 0, 0, 0);
    if (t + 2 < TS) {                    // prefetch t+2 into regs just consumed
#pragma unroll
      for (int kt = 0; kt < 4; ++kt)
        cur[kt] = *(const half8*)&hg[(size_t)(t + 2) * 2048 + kt * 512 + rbase];
    }
#pragma unroll
    for (int kt = 0; kt < 4; ++kt)
#pragma unroll
      for (int gt = 0; gt < 4; ++gt)
        acc[gt] = __builtin_amdgcn_mfma_f32_16x16x32_f16(ah[kt], bh[kt][gt], acc[gt], 0, 0, 0);
    const int wb = (t + 1) & 1;
    float hv4[4];
#pragma unroll
    for (int r = 0; r < 4; ++r) {
      float hv = lstm_cell(acc[0][r], acc[1][r], acc[2][r], acc[3][r], c[r]);
      _Float16 hh = (_Float16)hv;
      hb[wb][wbase + r * 8] = hh;
      hv4[r] = hv;
      if (t == TS - 1) h_last[(size_t)(gr0 + quad * 4 + r) * HID + col] = hh;
    }
#pragma unroll
    for (int r = 0; r < 4; ++r) { ssum += hv4[r]; ssq += hv4[r] * hv4[r]; }
  };

  for (int t = 0; t < TS; t += 2) {
    step(t, a2A);
    step(t + 1, a2B);
  }

  float s = ssum, q = ssq;
  s += __shfl_xor(s, 16); s += __shfl_xor(s, 32);
  q += __shfl_xor(q, 16); q += __shfl_xor(q, 32);
  if (quad == 0) {
    atomicAdd(&s2sum[inp * HID + col], s);
    atomicAdd(&s2sq[inp * HID + col], q);
  }
}

// ---------------------------------------------------------------------------
// Head: BN2 finalize + FC + L2 normalize. 96 WGs x 16 rows.
// ---------------------------------------------------------------------------
__global__ __launch_bounds__(256, 1) void head_kernel(
    const _Float16* __restrict__ h_last,
    const float* __restrict__ s2sum, const float* __restrict__ s2sq,
    const float* __restrict__ g2, const float* __restrict__ b2,
    const float* __restrict__ fcW, const float* __restrict__ fcb,
    float* __restrict__ out) {
  const int wg = blockIdx.x;
  const int inp = wg >> 5;
  const int gr0 = wg * 16;
  const int tid = threadIdx.x;

  __shared__ float fcwT[128][132];       // fcwT[h][j] = fcW[j][h]
  __shared__ float bnh[16][132];
  __shared__ float s2[128], sh2[128];
  __shared__ float part[16][16];
  __shared__ float inv[16];

  if (tid < 128) {
    float m = s2sum[inp * HID + tid] * INV_N;
    float v = s2sq[inp * HID + tid] * INV_N - m * m;
    float s = g2[tid] * rsqrtf(v + 1e-5f);
    s2[tid] = s; sh2[tid] = b2[tid] - m * s;
  }
  for (int i = tid; i < 16384; i += 256) {
    int j = i >> 7, h = i & 127;
    fcwT[h][j] = fcW[i];
  }
  __syncthreads();
  {
    int row = tid >> 4, c0 = (tid & 15) * 8;
#pragma unroll
    for (int k = 0; k < 8; ++k) {
      int h = c0 + k;
      bnh[row][h] = (float)h_last[(gr0 + row) * HID + h] * s2[h] + sh2[h];
    }
  }
  __syncthreads();
  const int row = tid >> 4, jl = tid & 15;
  float emb[8];
  float sq = 0.0f;
#pragma unroll
  for (int jj = 0; jj < 8; ++jj) {
    int j = jl + jj * 16;
    float acc = fcb[j];
    for (int h = 0; h < HID; ++h) acc += bnh[row][h] * fcwT[h][j];
    emb[jj] = acc; sq += acc * acc;
  }
  part[row][jl] = sq;
  __syncthreads();
  if (tid < 16) {
    float s = 0.0f;
    for (int k = 0; k < 16; ++k) s += part[tid][k];
    float nrm = sqrtf(s);
    inv[tid] = 1.0f / fmaxf(nrm, 1e-12f);
  }
  __syncthreads();
#pragma unroll
  for (int jj = 0; jj < 8; ++jj)
    out[(gr0 + row) * HID + jl + jj * 16] = emb[jj] * inv[row];
}

// ---------------------------------------------------------------------------
extern "C" void kernel_launch(void* const* d_in, const int* in_sizes, int n_in,
                              void* d_out, int out_size, void* d_ws, size_t ws_size,
                              hipStream_t stream) {
  const float* a    = (const float*)d_in[0];
  const float* p    = (const float*)d_in[1];
  const float* nn   = (const float*)d_in[2];
  const float* Wih1 = (const float*)d_in[3];
  const float* Whh1 = (const float*)d_in[4];
  const float* bih1 = (const float*)d_in[5];
  const float* bhh1 = (const float*)d_in[6];
  const float* g1   = (const float*)d_in[7];
  const float* b1   = (const float*)d_in[8];
  const float* Wih2 = (const float*)d_in[9];
  const float* Whh2 = (const float*)d_in[10];
  const float* bih2 = (const float*)d_in[11];
  const float* bhh2 = (const float*)d_in[12];
  const float* g2   = (const float*)d_in[13];
  const float* b2   = (const float*)d_in[14];
  const float* fcW  = (const float*)d_in[15];
  const float* fcb  = (const float*)d_in[16];

  char* ws = (char*)d_ws;
  float* s1sum = (float*)(ws + 0);            // 384 f32
  float* s1sq  = s1sum + 384;
  float* s2sum = s1sum + 768;
  float* s2sq  = s1sum + 1152;                // stats end @6144B
  float* b1c      = (float*)(ws + 6144);      // 512 f32 -> @8192
  float* bias2eff = (float*)(ws + 8192);      // 1536 f32 -> @14336
  _Float16* whhT1 = (_Float16*)(ws + 14336);    // 131072B -> @145408
  _Float16* whhT2 = (_Float16*)(ws + 145408);   // 131072B -> @276480
  _Float16* w2s   = (_Float16*)(ws + 276480);   // 393216B -> @669696
  _Float16* hlast = (_Float16*)(ws + 669696);   // 393216B -> @1062912
  _Float16* xpad  = (_Float16*)(ws + 1062912);  // 3145728B -> @4208640
  _Float16* hs1   = (_Float16*)(ws + 4208640);  // 50331648B -> ~54.5MB total

  prep_all<<<835, 256, 0, stream>>>(a, p, nn, Whh1, Whh2, bih1, bhh1,
                                    xpad, whhT1, whhT2, b1c, s1sum);
  lstm1_kernel<<<48, 512, 0, stream>>>(xpad, Wih1, b1c, whhT1, hs1, s1sum, s1sq);
  mid_kernel<<<102, 256, 0, stream>>>(s1sum, s1sq, g1, b1, Wih2, bih2, bhh2,
                                      w2s, bias2eff);
  lstm2_kernel<<<96, 512, 0, stream>>>(hs1, whhT2, w2s, bias2eff, hlast, s2sum, s2sq);
  head_kernel<<<96, 256, 0, stream>>>(hlast, s2sum, s2sq, g2, b2, fcW, fcb, (float*)d_out);
}

// Round 12
// 411.709 us; speedup vs baseline: 5.1392x; 1.0560x over previous
//
#include <hip/hip_runtime.h>
#include <hip/hip_cooperative_groups.h>

namespace cg = cooperative_groups;

// ============================================================================
// TypeNet triplet embedder. Round 15: single cooperative mega-kernel.
//  - R14 lesson: dual-per-wave gave 1.33x per-wave ILP but needed 2x to pay
//    for halved WG count -> reverted; lstm1/lstm2 are R8 bodies verbatim.
//  - All 5 dispatches + memset collapse into ONE cooperative kernel with
//    grid.sync() between phases: prep -> lstm1 -> mid -> lstm2 -> head.
//    Kills ~5 launch gaps + small-kernel overhead (~80us pool at R8).
//  - 96 WGs x 512, 79KB LDS union (lstm hb 8KB / head fcwT 68KB) -> all
//    blocks co-resident (requirement for cooperative launch).
//  - mid/prep phases keep R8's exact FP op order -> bit-identical gates.
//    head re-laned for 512 threads (norm partial order changes, ~1e-7).
// ============================================================================

typedef __attribute__((ext_vector_type(8))) _Float16 half8;
typedef __attribute__((ext_vector_type(4))) float f32x4;

#define TS 128
#define HID 128
#define NGATE 512
#define INV_N (1.0f/65536.0f)   // 1/(B*T)
#define NL2E  -1.4426950408889634f   // -log2(e)
#define N2L2E -2.8853900817779268f   // -2*log2(e)
#define GCLAMP 57.707801635558536f   // 20 * 2*log2(e)

#define BAR() asm volatile("s_waitcnt lgkmcnt(0)\n\ts_barrier" ::: "memory")

__device__ __forceinline__ float rcpf(float x) { return __builtin_amdgcn_rcpf(x); }
__device__ __forceinline__ float ex2(float x) { return __builtin_amdgcn_exp2f(x); }

// Gate pre-activations arrive PRE-SCALED: zi,zf,zo = -log2e*z, zg = -2log2e*z.
// 5 exp2 + 2 rcp per cell (merged f/ig denominator). R8-proven.
__device__ __forceinline__ float lstm_cell(float zi, float zf, float zg, float zo,
                                           float& c) {
  float zgc = __builtin_amdgcn_fmed3f(zg, -GCLAMP, GCLAMP);
  float ei = ex2(zi);
  float ef = ex2(zf);
  float eg = ex2(zgc);
  float eo = ex2(zo);
  float pi = 1.0f + ei, pg = 1.0f + eg, pf = 1.0f + ef;
  float P = pi * pg;
  float rd = rcpf(P * pf);
  float fv = P * rd;                    // sigmoid(zf)
  float ig = (1.0f - eg) * (pf * rd);   // sigmoid(zi)*tanh(zg)
  float cc = fv * c + ig;
  c = cc;
  float t2 = __builtin_amdgcn_fmed3f(cc * N2L2E, -GCLAMP, GCLAMP);
  float ec = ex2(t2);
  float hv = (1.0f - ec) * rcpf((1.0f + eo) * (1.0f + ec));  // sigmoid(zo)*tanh(cc)
  return hv;
}

// A-frag layout for a 16x128 fp16 tile:
//   addr(row, col) = (col>>5)*512 + ((col>>3)&3)*128 + row*8 + (col&7)
// Weight (B-frag): w[(kq*512+g)*8+j] = W^T[(kq>>2)*32+(kq&3)*8+j][g], gate-scaled.
// stats layout: s1sum[384]=stats+0, s1sq=+384, s2sum=+768, s2sq=+1152.

__global__ __launch_bounds__(512, 2) void mega_kernel(
    const float* __restrict__ xa, const float* __restrict__ xpi,
    const float* __restrict__ xn,
    const float* __restrict__ Wih1, const float* __restrict__ Whh1,
    const float* __restrict__ bih1, const float* __restrict__ bhh1,
    const float* __restrict__ g1, const float* __restrict__ b1,
    const float* __restrict__ Wih2, const float* __restrict__ Whh2,
    const float* __restrict__ bih2, const float* __restrict__ bhh2,
    const float* __restrict__ g2, const float* __restrict__ b2,
    const float* __restrict__ fcW, const float* __restrict__ fcb,
    float* __restrict__ out,
    float* __restrict__ stats, float* __restrict__ b1c,
    float* __restrict__ bias2eff,
    _Float16* __restrict__ whhT1, _Float16* __restrict__ whhT2,
    _Float16* __restrict__ w2s, _Float16* __restrict__ hlast,
    _Float16* __restrict__ xpad, _Float16* __restrict__ hs1) {
  const int wg = blockIdx.x;             // 0..95 (tile id for L1/L2/H)
  const int tid = threadIdx.x;           // 0..511
  const int gtid = wg * 512 + tid;       // 0..49151
  const int w = tid >> 6;
  const int lane = tid & 63;
  const int l15 = lane & 15;
  const int quad = lane >> 4;
  const int col = w * 16 + l15;
  const int inp = wg >> 5;

  __shared__ __align__(16) char smraw[79168];  // union: lstm hb(8KB)/head(77KB)
  cg::grid_group grid = cg::this_grid();

  // ======== Phase P: prep (xpad, whhT1/2, b1c, stats zero) ========
  {
    for (int i = gtid; i < 196608; i += 49152) {   // xpad half8 items
      int tile = i >> 11, rem = i & 2047;
      int t = rem >> 4, r = rem & 15;
      int ip = tile >> 5, rloc = (tile & 31) * 16;
      const float* x = (ip == 0) ? xa : ((ip == 1) ? xpi : xn);
      const float* row = x + (size_t)(rloc + r) * 640 + t * 5;
      half8 v = {0, 0, 0, 0, 0, 0, 0, 0};
#pragma unroll
      for (int j = 0; j < 5; ++j) v[j] = (_Float16)row[j];
      *(half8*)&xpad[(size_t)i * 8] = v;
    }
    if (gtid < 16384) {                            // whhT1/2 B-frag, scaled
      int which = gtid >> 13, i8 = gtid & 8191;
      int kq = i8 >> 9, g = i8 & 511;
      int k0 = (kq >> 2) * 32 + (kq & 3) * 8;
      float gs = ((g >> 7) == 2) ? N2L2E : NL2E;
      const float* src = which ? Whh2 : Whh1;
      half8 v;
#pragma unroll
      for (int j = 0; j < 8; ++j) v[j] = (_Float16)(src[(size_t)g * HID + k0 + j] * gs);
      *(half8*)&(which ? whhT2 : whhT1)[(size_t)i8 * 8] = v;
    }
    if (gtid < 512) {                              // b1c, gate-scaled
      float gs = ((gtid >> 7) == 2) ? N2L2E : NL2E;
      b1c[gtid] = (bih1[gtid] + bhh1[gtid]) * gs;
    }
    if (gtid < 1536) stats[gtid] = 0.0f;           // zero BN stats
  }
  grid.sync();

  // ======== Phase L1: LSTM layer 1 (R8 body, tile = wg) ========
  {
    _Float16* hb = (_Float16*)smraw;               // [2][2048]
    for (int i = tid; i < 4096; i += 512) hb[i] = (_Float16)0.0f;

    const int rbase = (quad * 16 + l15) * 8;
    const int wbase = (w >> 1) * 512 + ((w & 1) * 2 + (l15 >> 3)) * 128 +
                      quad * 32 + (l15 & 7);

    half8 bh[4][4];
#pragma unroll
    for (int kt = 0; kt < 4; ++kt)
#pragma unroll
      for (int gt = 0; gt < 4; ++gt)
        bh[kt][gt] = *(const half8*)&whhT1[(size_t)((kt * 4 + quad) * 512 + gt * 128 + col) * 8];

    half8 bx[4];
#pragma unroll
    for (int gt = 0; gt < 4; ++gt) {
      half8 v = {0, 0, 0, 0, 0, 0, 0, 0};
      if (quad == 0) {
        float gs = (gt == 2) ? N2L2E : NL2E;
#pragma unroll
        for (int j = 0; j < 5; ++j) v[j] = (_Float16)(Wih1[(gt * 128 + col) * 5 + j] * gs);
      }
      bx[gt] = v;
    }
    f32x4 biasv[4];
#pragma unroll
    for (int gt = 0; gt < 4; ++gt) {
      float b = b1c[gt * 128 + col];
      biasv[gt][0] = b; biasv[gt][1] = b; biasv[gt][2] = b; biasv[gt][3] = b;
    }

    half8 xp8 = {0, 0, 0, 0, 0, 0, 0, 0};
    if (quad == 0) xp8 = *(const half8*)&xpad[((size_t)(wg * TS) * 16 + l15) * 8];

    float c4[4] = {0, 0, 0, 0};
    float ssum = 0.0f, ssq = 0.0f;
    _Float16* hs1w = hs1 + (size_t)wg * TS * 2048;

    for (int t = 0; t < TS; ++t) {
      BAR();                             // h(t-1) (and t=0 zero-init) visible
      half8 ah[4];
#pragma unroll
      for (int kt = 0; kt < 4; ++kt)
        ah[kt] = *(const half8*)&hb[(t & 1) * 2048 + kt * 512 + rbase];
      if (t > 0) {
        float2 cp = *(const float2*)&hb[(t & 1) * 2048 + tid * 4];
        *(float2*)&hs1w[(size_t)(t - 1) * 2048 + tid * 4] = cp;
      }
      f32x4 acc[4];
#pragma unroll
      for (int gt = 0; gt < 4; ++gt)
        acc[gt] = __builtin_amdgcn_mfma_f32_16x16x32_f16(xp8, bx[gt], biasv[gt], 0, 0, 0);
      if (t + 1 < TS && quad == 0)
        xp8 = *(const half8*)&xpad[((size_t)(wg * TS + t + 1) * 16 + l15) * 8];
#pragma unroll
      for (int kt = 0; kt < 4; ++kt)
#pragma unroll
        for (int gt = 0; gt < 4; ++gt)
          acc[gt] = __builtin_amdgcn_mfma_f32_16x16x32_f16(ah[kt], bh[kt][gt], acc[gt], 0, 0, 0);
      const int wb = (t + 1) & 1;
      float hv4[4];
#pragma unroll
      for (int r = 0; r < 4; ++r) {
        float hv = lstm_cell(acc[0][r], acc[1][r], acc[2][r], acc[3][r], c4[r]);
        hb[wb * 2048 + wbase + r * 8] = (_Float16)hv;
        hv4[r] = hv;
      }
#pragma unroll
      for (int r = 0; r < 4; ++r) { ssum += hv4[r]; ssq += hv4[r] * hv4[r]; }
    }
    BAR();                               // h(127) visible
    {
      float2 cp = *(const float2*)&hb[tid * 4];
      *(float2*)&hs1w[(size_t)(TS - 1) * 2048 + tid * 4] = cp;
    }
    float s = ssum, q = ssq;
    s += __shfl_xor(s, 16); s += __shfl_xor(s, 32);
    q += __shfl_xor(q, 16); q += __shfl_xor(q, 32);
    if (quad == 0) {
      atomicAdd(&stats[inp * HID + col], s);         // s1sum
      atomicAdd(&stats[384 + inp * HID + col], q);   // s1sq
    }
  }
  grid.sync();

  // ======== Phase M: BN1-folded W2 + effective bias2 (inline) ========
  {
    if (gtid < 24576) {                  // w2s: [3][16 kq][512 g][8]
      int ip = gtid >> 13, i8 = gtid & 8191;
      int kq = i8 >> 9, g = i8 & 511;
      int k0 = (kq >> 2) * 32 + (kq & 3) * 8;
      float gs = ((g >> 7) == 2) ? N2L2E : NL2E;
      const float* wr = Wih2 + (size_t)g * HID + k0;
      half8 v;
#pragma unroll
      for (int j = 0; j < 8; ++j) {
        int k = k0 + j;
        float m = stats[ip * HID + k] * INV_N;
        float vv = stats[384 + ip * HID + k] * INV_N - m * m;
        float sc = g1[k] * rsqrtf(vv + 1e-5f);
        v[j] = (_Float16)(sc * wr[j] * gs);
      }
      *(half8*)&w2s[(size_t)gtid * 8] = v;
    } else if (gtid < 26112) {           // bias2eff: [3][512]
      int i = gtid - 24576;
      int ip = i >> 9, g = i & 511;
      float acc = bih2[g] + bhh2[g];
      const float* wr = Wih2 + (size_t)g * HID;
      for (int h = 0; h < HID; ++h) {
        float m = stats[ip * HID + h] * INV_N;
        float vv = stats[384 + ip * HID + h] * INV_N - m * m;
        float s = g1[h] * rsqrtf(vv + 1e-5f);
        acc += (b1[h] - m * s) * wr[h];
      }
      float gs = ((g >> 7) == 2) ? N2L2E : NL2E;
      bias2eff[i] = acc * gs;
    }
  }
  grid.sync();

  // ======== Phase L2: LSTM layer 2 (R8 body, tile = wg) ========
  {
    _Float16* hb = (_Float16*)smraw;               // [2][2048]
    for (int i = tid; i < 4096; i += 512) hb[i] = (_Float16)0.0f;

    const int gr0 = wg * 16;
    const int rbase = (quad * 16 + l15) * 8;
    const int wbase = (w >> 1) * 512 + ((w & 1) * 2 + (l15 >> 3)) * 128 +
                      quad * 32 + (l15 & 7);

    const _Float16* w2sI = w2s + (size_t)inp * HID * NGATE;
    half8 bh[4][4], bxw[4][4];
#pragma unroll
    for (int kt = 0; kt < 4; ++kt)
#pragma unroll
      for (int gt = 0; gt < 4; ++gt) {
        size_t gi = (size_t)((kt * 4 + quad) * 512 + gt * 128 + col) * 8;
        bh[kt][gt] = *(const half8*)&whhT2[gi];
        bxw[kt][gt] = *(const half8*)&w2sI[gi];
      }
    f32x4 biasv[4];
#pragma unroll
    for (int gt = 0; gt < 4; ++gt) {
      float b = bias2eff[inp * NGATE + gt * 128 + col];
      biasv[gt][0] = b; biasv[gt][1] = b; biasv[gt][2] = b; biasv[gt][3] = b;
    }

    const _Float16* hg = hs1 + (size_t)wg * TS * 2048;
    half8 a2A[4], a2B[4];
#pragma unroll
    for (int kt = 0; kt < 4; ++kt) {
      a2A[kt] = *(const half8*)&hg[kt * 512 + rbase];
      a2B[kt] = *(const half8*)&hg[(size_t)2048 + kt * 512 + rbase];
    }

    float c4[4] = {0, 0, 0, 0};
    float ssum = 0.0f, ssq = 0.0f;

    auto step = [&](int t, half8 (&cur)[4]) {
      BAR();                             // h(t-1) visible; vmcnt untouched
      half8 ah[4];
#pragma unroll
      for (int kt = 0; kt < 4; ++kt)
        ah[kt] = *(const half8*)&hb[(t & 1) * 2048 + kt * 512 + rbase];
      f32x4 acc[4];
#pragma unroll
      for (int gt = 0; gt < 4; ++gt)
        acc[gt] = __builtin_amdgcn_mfma_f32_16x16x32_f16(cur[0], bxw[0][gt], biasv[gt], 0, 0, 0);
#pragma unroll
      for (int kt = 1; kt < 4; ++kt)
#pragma unroll
        for (int gt = 0; gt < 4; ++gt)
          acc[gt] = __builtin_amdgcn_mfma_f32_16x16x32_f16(cur[kt], bxw[kt][gt], acc[gt], 0, 0, 0);
      if (t + 2 < TS) {
#pragma unroll
        for (int kt = 0; kt < 4; ++kt)
          cur[kt] = *(const half8*)&hg[(size_t)(t + 2) * 2048 + kt * 512 + rbase];
      }
#pragma unroll
      for (int kt = 0; kt < 4; ++kt)
#pragma unroll
        for (int gt = 0; gt < 4; ++gt)
          acc[gt] = __builtin_amdgcn_mfma_f32_16x16x32_f16(ah[kt], bh[kt][gt], acc[gt], 0, 0, 0);
      const int wb = (t + 1) & 1;
      float hv4[4];
#pragma unroll
      for (int r = 0; r < 4; ++r) {
        float hv = lstm_cell(acc[0][r], acc[1][r], acc[2][r], acc[3][r], c4[r]);
        _Float16 hh = (_Float16)hv;
        hb[wb * 2048 + wbase + r * 8] = hh;
        hv4[r] = hv;
        if (t == TS - 1) hlast[(size_t)(gr0 + quad * 4 + r) * HID + col] = hh;
      }
#pragma unroll
      for (int r = 0; r < 4; ++r) { ssum += hv4[r]; ssq += hv4[r] * hv4[r]; }
    };

    for (int t = 0; t < TS; t += 2) {
      step(t, a2A);
      step(t + 1, a2B);
    }

    float s = ssum, q = ssq;
    s += __shfl_xor(s, 16); s += __shfl_xor(s, 32);
    q += __shfl_xor(q, 16); q += __shfl_xor(q, 32);
    if (quad == 0) {
      atomicAdd(&stats[768 + inp * HID + col], s);    // s2sum
      atomicAdd(&stats[1152 + inp * HID + col], q);   // s2sq
    }
  }
  grid.sync();

  // ======== Phase H: BN2 + FC + L2 normalize (512-thread layout) ========
  {
    float* fcwT = (float*)smraw;                   // [128][132]
    float* bnh  = fcwT + 128 * 132;                // [16][132]
    float* s2v  = bnh + 16 * 132;                  // [128]
    float* sh2v = s2v + 128;                       // [128]
    float* part = sh2v + 128;                      // [16][32]
    float* inv  = part + 16 * 32;                  // [16]
    const int gr0 = wg * 16;

    if (tid < 128) {
      float m = stats[768 + inp * HID + tid] * INV_N;
      float v = stats[1152 + inp * HID + tid] * INV_N - m * m;
      float s = g2[tid] * rsqrtf(v + 1e-5f);
      s2v[tid] = s; sh2v[tid] = b2[tid] - m * s;
    }
    for (int i = tid; i < 16384; i += 512) {
      int j = i >> 7, h = i & 127;
      fcwT[h * 132 + j] = fcW[i];
    }
    __syncthreads();
    {
      int row = tid >> 5, c0 = (tid & 31) * 4;
#pragma unroll
      for (int k = 0; k < 4; ++k) {
        int h = c0 + k;
        bnh[row * 132 + h] = (float)hlast[(gr0 + row) * HID + h] * s2v[h] + sh2v[h];
      }
    }
    __syncthreads();
    const int row = tid >> 5, jl = tid & 31;
    float emb[4];
    float sq = 0.0f;
#pragma unroll
    for (int jj = 0; jj < 4; ++jj) {
      int j = jl + jj * 32;
      float acc = fcb[j];
      for (int h = 0; h < HID; ++h) acc += bnh[row * 132 + h] * fcwT[h * 132 + j];
      emb[jj] = acc; sq += acc * acc;
    }
    part[row * 32 + jl] = sq;
    __syncthreads();
    if (tid < 16) {
      float s = 0.0f;
      for (int k = 0; k < 32; ++k) s += part[tid * 32 + k];
      inv[tid] = 1.0f / fmaxf(sqrtf(s), 1e-12f);
    }
    __syncthreads();
#pragma unroll
    for (int jj = 0; jj < 4; ++jj)
      out[(gr0 + row) * HID + jl + jj * 32] = emb[jj] * inv[row];
  }
}

// ---------------------------------------------------------------------------
extern "C" void kernel_launch(void* const* d_in, const int* in_sizes, int n_in,
                              void* d_out, int out_size, void* d_ws, size_t ws_size,
                              hipStream_t stream) {
  const float* a    = (const float*)d_in[0];
  const float* p    = (const float*)d_in[1];
  const float* nn   = (const float*)d_in[2];
  const float* Wih1 = (const float*)d_in[3];
  const float* Whh1 = (const float*)d_in[4];
  const float* bih1 = (const float*)d_in[5];
  const float* bhh1 = (const float*)d_in[6];
  const float* g1   = (const float*)d_in[7];
  const float* b1   = (const float*)d_in[8];
  const float* Wih2 = (const float*)d_in[9];
  const float* Whh2 = (const float*)d_in[10];
  const float* bih2 = (const float*)d_in[11];
  const float* bhh2 = (const float*)d_in[12];
  const float* g2   = (const float*)d_in[13];
  const float* b2   = (const float*)d_in[14];
  const float* fcW  = (const float*)d_in[15];
  const float* fcb  = (const float*)d_in[16];

  char* ws = (char*)d_ws;
  float* stats    = (float*)(ws + 0);         // 1536 f32: s1sum,s1sq,s2sum,s2sq
  float* b1c      = (float*)(ws + 6144);      // 512 f32
  float* bias2eff = (float*)(ws + 8192);      // 1536 f32
  _Float16* whhT1 = (_Float16*)(ws + 14336);    // 131072B
  _Float16* whhT2 = (_Float16*)(ws + 145408);   // 131072B
  _Float16* w2s   = (_Float16*)(ws + 276480);   // 393216B
  _Float16* hlast = (_Float16*)(ws + 669696);   // 393216B
  _Float16* xpad  = (_Float16*)(ws + 1062912);  // 3145728B
  _Float16* hs1   = (_Float16*)(ws + 4208640);  // 50331648B -> ~54.5MB total
  float* outp = (float*)d_out;

  void* args[] = {
    (void*)&a, (void*)&p, (void*)&nn,
    (void*)&Wih1, (void*)&Whh1, (void*)&bih1, (void*)&bhh1,
    (void*)&g1, (void*)&b1,
    (void*)&Wih2, (void*)&Whh2, (void*)&bih2, (void*)&bhh2,
    (void*)&g2, (void*)&b2, (void*)&fcW, (void*)&fcb,
    (void*)&outp,
    (void*)&stats, (void*)&b1c, (void*)&bias2eff,
    (void*)&whhT1, (void*)&whhT2, (void*)&w2s, (void*)&hlast,
    (void*)&xpad, (void*)&hs1
  };
  hipLaunchCooperativeKernel(mega_kernel, dim3(96), dim3(512), args, 0u, stream);
}

// Round 13
// 388.726 us; speedup vs baseline: 5.4430x; 1.0591x over previous
//
#include <hip/hip_runtime.h>

// ============================================================================
// TypeNet triplet embedder. Round 16: mega-kernel with SOFTWARE grid barrier.
//  - R15 measured: fused phases = 303.9us device time (vs R8's 337 total) but
//    hipLaunchCooperativeKernel added ~108us launch overhead (not graph-
//    capturable). Same kernel body, grid.sync() -> device-scope atomic
//    barrier, plain <<<96,512>>> launch (graph-capturable).
//  - Barrier: monotonic counter in workspace, zeroed by 4B hipMemsetAsync.
//    __hip_atomic_* with AGENT scope handles cross-XCD L2 non-coherence.
//    96 blocks x 79KB LDS -> all co-resident (<=2 blocks/CU), no deadlock.
//  - Phases: prep -> lstm1 (R8 body) -> mid -> lstm2 (R8 body) -> head.
// ============================================================================

typedef __attribute__((ext_vector_type(8))) _Float16 half8;
typedef __attribute__((ext_vector_type(4))) float f32x4;

#define TS 128
#define HID 128
#define NGATE 512
#define INV_N (1.0f/65536.0f)   // 1/(B*T)
#define NL2E  -1.4426950408889634f   // -log2(e)
#define N2L2E -2.8853900817779268f   // -2*log2(e)
#define GCLAMP 57.707801635558536f   // 20 * 2*log2(e)

#define BAR() asm volatile("s_waitcnt lgkmcnt(0)\n\ts_barrier" ::: "memory")

__device__ __forceinline__ float rcpf(float x) { return __builtin_amdgcn_rcpf(x); }
__device__ __forceinline__ float ex2(float x) { return __builtin_amdgcn_exp2f(x); }

// Device-scope grid barrier: monotonic counter, target = 96*phase.
__device__ __forceinline__ void grid_bar(unsigned* cnt, unsigned expect) {
  __syncthreads();
  if (threadIdx.x == 0) {
    __hip_atomic_fetch_add(cnt, 1u, __ATOMIC_ACQ_REL, __HIP_MEMORY_SCOPE_AGENT);
    while (__hip_atomic_load(cnt, __ATOMIC_ACQUIRE, __HIP_MEMORY_SCOPE_AGENT) < expect)
      __builtin_amdgcn_s_sleep(8);
  }
  __syncthreads();
}

// Gate pre-activations arrive PRE-SCALED: zi,zf,zo = -log2e*z, zg = -2log2e*z.
// 5 exp2 + 2 rcp per cell (merged f/ig denominator). R8-proven.
__device__ __forceinline__ float lstm_cell(float zi, float zf, float zg, float zo,
                                           float& c) {
  float zgc = __builtin_amdgcn_fmed3f(zg, -GCLAMP, GCLAMP);
  float ei = ex2(zi);
  float ef = ex2(zf);
  float eg = ex2(zgc);
  float eo = ex2(zo);
  float pi = 1.0f + ei, pg = 1.0f + eg, pf = 1.0f + ef;
  float P = pi * pg;
  float rd = rcpf(P * pf);
  float fv = P * rd;                    // sigmoid(zf)
  float ig = (1.0f - eg) * (pf * rd);   // sigmoid(zi)*tanh(zg)
  float cc = fv * c + ig;
  c = cc;
  float t2 = __builtin_amdgcn_fmed3f(cc * N2L2E, -GCLAMP, GCLAMP);
  float ec = ex2(t2);
  float hv = (1.0f - ec) * rcpf((1.0f + eo) * (1.0f + ec));  // sigmoid(zo)*tanh(cc)
  return hv;
}

// A-frag layout for a 16x128 fp16 tile:
//   addr(row, col) = (col>>5)*512 + ((col>>3)&3)*128 + row*8 + (col&7)
// Weight (B-frag): w[(kq*512+g)*8+j] = W^T[(kq>>2)*32+(kq&3)*8+j][g], gate-scaled.
// stats layout: s1sum[384]=stats+0, s1sq=+384, s2sum=+768, s2sq=+1152.

__global__ __launch_bounds__(512, 2) void mega_kernel(
    const float* __restrict__ xa, const float* __restrict__ xpi,
    const float* __restrict__ xn,
    const float* __restrict__ Wih1, const float* __restrict__ Whh1,
    const float* __restrict__ bih1, const float* __restrict__ bhh1,
    const float* __restrict__ g1, const float* __restrict__ b1,
    const float* __restrict__ Wih2, const float* __restrict__ Whh2,
    const float* __restrict__ bih2, const float* __restrict__ bhh2,
    const float* __restrict__ g2, const float* __restrict__ b2,
    const float* __restrict__ fcW, const float* __restrict__ fcb,
    float* __restrict__ out,
    float* __restrict__ stats, float* __restrict__ b1c,
    float* __restrict__ bias2eff,
    _Float16* __restrict__ whhT1, _Float16* __restrict__ whhT2,
    _Float16* __restrict__ w2s, _Float16* __restrict__ hlast,
    _Float16* __restrict__ xpad, _Float16* __restrict__ hs1,
    unsigned* __restrict__ bar) {
  const int wg = blockIdx.x;             // 0..95 (tile id for L1/L2/H)
  const int tid = threadIdx.x;           // 0..511
  const int gtid = wg * 512 + tid;       // 0..49151
  const int w = tid >> 6;
  const int lane = tid & 63;
  const int l15 = lane & 15;
  const int quad = lane >> 4;
  const int col = w * 16 + l15;
  const int inp = wg >> 5;

  __shared__ __align__(16) char smraw[79168];  // union: lstm hb(8KB)/head(77KB)

  // ======== Phase P: prep (xpad, whhT1/2, b1c, stats zero) ========
  {
    for (int i = gtid; i < 196608; i += 49152) {   // xpad half8 items
      int tile = i >> 11, rem = i & 2047;
      int t = rem >> 4, r = rem & 15;
      int ip = tile >> 5, rloc = (tile & 31) * 16;
      const float* x = (ip == 0) ? xa : ((ip == 1) ? xpi : xn);
      const float* row = x + (size_t)(rloc + r) * 640 + t * 5;
      half8 v = {0, 0, 0, 0, 0, 0, 0, 0};
#pragma unroll
      for (int j = 0; j < 5; ++j) v[j] = (_Float16)row[j];
      *(half8*)&xpad[(size_t)i * 8] = v;
    }
    if (gtid < 16384) {                            // whhT1/2 B-frag, scaled
      int which = gtid >> 13, i8 = gtid & 8191;
      int kq = i8 >> 9, g = i8 & 511;
      int k0 = (kq >> 2) * 32 + (kq & 3) * 8;
      float gs = ((g >> 7) == 2) ? N2L2E : NL2E;
      const float* src = which ? Whh2 : Whh1;
      half8 v;
#pragma unroll
      for (int j = 0; j < 8; ++j) v[j] = (_Float16)(src[(size_t)g * HID + k0 + j] * gs);
      *(half8*)&(which ? whhT2 : whhT1)[(size_t)i8 * 8] = v;
    }
    if (gtid < 512) {                              // b1c, gate-scaled
      float gs = ((gtid >> 7) == 2) ? N2L2E : NL2E;
      b1c[gtid] = (bih1[gtid] + bhh1[gtid]) * gs;
    }
    if (gtid < 1536) stats[gtid] = 0.0f;           // zero BN stats
  }
  grid_bar(bar, 96);

  // ======== Phase L1: LSTM layer 1 (R8 body, tile = wg) ========
  {
    _Float16* hb = (_Float16*)smraw;               // [2][2048]
    for (int i = tid; i < 4096; i += 512) hb[i] = (_Float16)0.0f;

    const int rbase = (quad * 16 + l15) * 8;
    const int wbase = (w >> 1) * 512 + ((w & 1) * 2 + (l15 >> 3)) * 128 +
                      quad * 32 + (l15 & 7);

    half8 bh[4][4];
#pragma unroll
    for (int kt = 0; kt < 4; ++kt)
#pragma unroll
      for (int gt = 0; gt < 4; ++gt)
        bh[kt][gt] = *(const half8*)&whhT1[(size_t)((kt * 4 + quad) * 512 + gt * 128 + col) * 8];

    half8 bx[4];
#pragma unroll
    for (int gt = 0; gt < 4; ++gt) {
      half8 v = {0, 0, 0, 0, 0, 0, 0, 0};
      if (quad == 0) {
        float gs = (gt == 2) ? N2L2E : NL2E;
#pragma unroll
        for (int j = 0; j < 5; ++j) v[j] = (_Float16)(Wih1[(gt * 128 + col) * 5 + j] * gs);
      }
      bx[gt] = v;
    }
    f32x4 biasv[4];
#pragma unroll
    for (int gt = 0; gt < 4; ++gt) {
      float b = b1c[gt * 128 + col];
      biasv[gt][0] = b; biasv[gt][1] = b; biasv[gt][2] = b; biasv[gt][3] = b;
    }

    half8 xp8 = {0, 0, 0, 0, 0, 0, 0, 0};
    if (quad == 0) xp8 = *(const half8*)&xpad[((size_t)(wg * TS) * 16 + l15) * 8];

    float c4[4] = {0, 0, 0, 0};
    float ssum = 0.0f, ssq = 0.0f;
    _Float16* hs1w = hs1 + (size_t)wg * TS * 2048;

    for (int t = 0; t < TS; ++t) {
      BAR();                             // h(t-1) (and t=0 zero-init) visible
      half8 ah[4];
#pragma unroll
      for (int kt = 0; kt < 4; ++kt)
        ah[kt] = *(const half8*)&hb[(t & 1) * 2048 + kt * 512 + rbase];
      if (t > 0) {
        float2 cp = *(const float2*)&hb[(t & 1) * 2048 + tid * 4];
        *(float2*)&hs1w[(size_t)(t - 1) * 2048 + tid * 4] = cp;
      }
      f32x4 acc[4];
#pragma unroll
      for (int gt = 0; gt < 4; ++gt)
        acc[gt] = __builtin_amdgcn_mfma_f32_16x16x32_f16(xp8, bx[gt], biasv[gt], 0, 0, 0);
      if (t + 1 < TS && quad == 0)
        xp8 = *(const half8*)&xpad[((size_t)(wg * TS + t + 1) * 16 + l15) * 8];
#pragma unroll
      for (int kt = 0; kt < 4; ++kt)
#pragma unroll
        for (int gt = 0; gt < 4; ++gt)
          acc[gt] = __builtin_amdgcn_mfma_f32_16x16x32_f16(ah[kt], bh[kt][gt], acc[gt], 0, 0, 0);
      const int wb = (t + 1) & 1;
      float hv4[4];
#pragma unroll
      for (int r = 0; r < 4; ++r) {
        float hv = lstm_cell(acc[0][r], acc[1][r], acc[2][r], acc[3][r], c4[r]);
        hb[wb * 2048 + wbase + r * 8] = (_Float16)hv;
        hv4[r] = hv;
      }
#pragma unroll
      for (int r = 0; r < 4; ++r) { ssum += hv4[r]; ssq += hv4[r] * hv4[r]; }
    }
    BAR();                               // h(127) visible
    {
      float2 cp = *(const float2*)&hb[tid * 4];
      *(float2*)&hs1w[(size_t)(TS - 1) * 2048 + tid * 4] = cp;
    }
    float s = ssum, q = ssq;
    s += __shfl_xor(s, 16); s += __shfl_xor(s, 32);
    q += __shfl_xor(q, 16); q += __shfl_xor(q, 32);
    if (quad == 0) {
      atomicAdd(&stats[inp * HID + col], s);         // s1sum
      atomicAdd(&stats[384 + inp * HID + col], q);   // s1sq
    }
  }
  grid_bar(bar, 192);

  // ======== Phase M: BN1-folded W2 + effective bias2 (inline) ========
  {
    if (gtid < 24576) {                  // w2s: [3][16 kq][512 g][8]
      int ip = gtid >> 13, i8 = gtid & 8191;
      int kq = i8 >> 9, g = i8 & 511;
      int k0 = (kq >> 2) * 32 + (kq & 3) * 8;
      float gs = ((g >> 7) == 2) ? N2L2E : NL2E;
      const float* wr = Wih2 + (size_t)g * HID + k0;
      half8 v;
#pragma unroll
      for (int j = 0; j < 8; ++j) {
        int k = k0 + j;
        float m = stats[ip * HID + k] * INV_N;
        float vv = stats[384 + ip * HID + k] * INV_N - m * m;
        float sc = g1[k] * rsqrtf(vv + 1e-5f);
        v[j] = (_Float16)(sc * wr[j] * gs);
      }
      *(half8*)&w2s[(size_t)gtid * 8] = v;
    } else if (gtid < 26112) {           // bias2eff: [3][512]
      int i = gtid - 24576;
      int ip = i >> 9, g = i & 511;
      float acc = bih2[g] + bhh2[g];
      const float* wr = Wih2 + (size_t)g * HID;
      for (int h = 0; h < HID; ++h) {
        float m = stats[ip * HID + h] * INV_N;
        float vv = stats[384 + ip * HID + h] * INV_N - m * m;
        float s = g1[h] * rsqrtf(vv + 1e-5f);
        acc += (b1[h] - m * s) * wr[h];
      }
      float gs = ((g >> 7) == 2) ? N2L2E : NL2E;
      bias2eff[i] = acc * gs;
    }
  }
  grid_bar(bar, 288);

  // ======== Phase L2: LSTM layer 2 (R8 body, tile = wg) ========
  {
    _Float16* hb = (_Float16*)smraw;               // [2][2048]
    for (int i = tid; i < 4096; i += 512) hb[i] = (_Float16)0.0f;

    const int gr0 = wg * 16;
    const int rbase = (quad * 16 + l15) * 8;
    const int wbase = (w >> 1) * 512 + ((w & 1) * 2 + (l15 >> 3)) * 128 +
                      quad * 32 + (l15 & 7);

    const _Float16* w2sI = w2s + (size_t)inp * HID * NGATE;
    half8 bh[4][4], bxw[4][4];
#pragma unroll
    for (int kt = 0; kt < 4; ++kt)
#pragma unroll
      for (int gt = 0; gt < 4; ++gt) {
        size_t gi = (size_t)((kt * 4 + quad) * 512 + gt * 128 + col) * 8;
        bh[kt][gt] = *(const half8*)&whhT2[gi];
        bxw[kt][gt] = *(const half8*)&w2sI[gi];
      }
    f32x4 biasv[4];
#pragma unroll
    for (int gt = 0; gt < 4; ++gt) {
      float b = bias2eff[inp * NGATE + gt * 128 + col];
      biasv[gt][0] = b; biasv[gt][1] = b; biasv[gt][2] = b; biasv[gt][3] = b;
    }

    const _Float16* hg = hs1 + (size_t)wg * TS * 2048;
    half8 a2A[4], a2B[4];
#pragma unroll
    for (int kt = 0; kt < 4; ++kt) {
      a2A[kt] = *(const half8*)&hg[kt * 512 + rbase];
      a2B[kt] = *(const half8*)&hg[(size_t)2048 + kt * 512 + rbase];
    }

    float c4[4] = {0, 0, 0, 0};
    float ssum = 0.0f, ssq = 0.0f;

    auto step = [&](int t, half8 (&cur)[4]) {
      BAR();                             // h(t-1) visible; vmcnt untouched
      half8 ah[4];
#pragma unroll
      for (int kt = 0; kt < 4; ++kt)
        ah[kt] = *(const half8*)&hb[(t & 1) * 2048 + kt * 512 + rbase];
      f32x4 acc[4];
#pragma unroll
      for (int gt = 0; gt < 4; ++gt)
        acc[gt] = __builtin_amdgcn_mfma_f32_16x16x32_f16(cur[0], bxw[0][gt], biasv[gt], 0, 0, 0);
#pragma unroll
      for (int kt = 1; kt < 4; ++kt)
#pragma unroll
        for (int gt = 0; gt < 4; ++gt)
          acc[gt] = __builtin_amdgcn_mfma_f32_16x16x32_f16(cur[kt], bxw[kt][gt], acc[gt], 0, 0, 0);
      if (t + 2 < TS) {
#pragma unroll
        for (int kt = 0; kt < 4; ++kt)
          cur[kt] = *(const half8*)&hg[(size_t)(t + 2) * 2048 + kt * 512 + rbase];
      }
#pragma unroll
      for (int kt = 0; kt < 4; ++kt)
#pragma unroll
        for (int gt = 0; gt < 4; ++gt)
          acc[gt] = __builtin_amdgcn_mfma_f32_16x16x32_f16(ah[kt], bh[kt][gt], acc[gt], 0, 0, 0);
      const int wb = (t + 1) & 1;
      float hv4[4];
#pragma unroll
      for (int r = 0; r < 4; ++r) {
        float hv = lstm_cell(acc[0][r], acc[1][r], acc[2][r], acc[3][r], c4[r]);
        _Float16 hh = (_Float16)hv;
        hb[wb * 2048 + wbase + r * 8] = hh;
        hv4[r] = hv;
        if (t == TS - 1) hlast[(size_t)(gr0 + quad * 4 + r) * HID + col] = hh;
      }
#pragma unroll
      for (int r = 0; r < 4; ++r) { ssum += hv4[r]; ssq += hv4[r] * hv4[r]; }
    };

    for (int t = 0; t < TS; t += 2) {
      step(t, a2A);
      step(t + 1, a2B);
    }

    float s = ssum, q = ssq;
    s += __shfl_xor(s, 16); s += __shfl_xor(s, 32);
    q += __shfl_xor(q, 16); q += __shfl_xor(q, 32);
    if (quad == 0) {
      atomicAdd(&stats[768 + inp * HID + col], s);    // s2sum
      atomicAdd(&stats[1152 + inp * HID + col], q);   // s2sq
    }
  }
  grid_bar(bar, 384);

  // ======== Phase H: BN2 + FC + L2 normalize (512-thread layout) ========
  {
    float* fcwT = (float*)smraw;                   // [128][132]
    float* bnh  = fcwT + 128 * 132;                // [16][132]
    float* s2v  = bnh + 16 * 132;                  // [128]
    float* sh2v = s2v + 128;                       // [128]
    float* part = sh2v + 128;                      // [16][32]
    float* inv  = part + 16 * 32;                  // [16]
    const int gr0 = wg * 16;

    if (tid < 128) {
      float m = stats[768 + inp * HID + tid] * INV_N;
      float v = stats[1152 + inp * HID + tid] * INV_N - m * m;
      float s = g2[tid] * rsqrtf(v + 1e-5f);
      s2v[tid] = s; sh2v[tid] = b2[tid] - m * s;
    }
    for (int i = tid; i < 16384; i += 512) {
      int j = i >> 7, h = i & 127;
      fcwT[h * 132 + j] = fcW[i];
    }
    __syncthreads();
    {
      int row = tid >> 5, c0 = (tid & 31) * 4;
#pragma unroll
      for (int k = 0; k < 4; ++k) {
        int h = c0 + k;
        bnh[row * 132 + h] = (float)hlast[(gr0 + row) * HID + h] * s2v[h] + sh2v[h];
      }
    }
    __syncthreads();
    const int row = tid >> 5, jl = tid & 31;
    float emb[4];
    float sq = 0.0f;
#pragma unroll
    for (int jj = 0; jj < 4; ++jj) {
      int j = jl + jj * 32;
      float acc = fcb[j];
      for (int h = 0; h < HID; ++h) acc += bnh[row * 132 + h] * fcwT[h * 132 + j];
      emb[jj] = acc; sq += acc * acc;
    }
    part[row * 32 + jl] = sq;
    __syncthreads();
    if (tid < 16) {
      float s = 0.0f;
      for (int k = 0; k < 32; ++k) s += part[tid * 32 + k];
      inv[tid] = 1.0f / fmaxf(sqrtf(s), 1e-12f);
    }
    __syncthreads();
#pragma unroll
    for (int jj = 0; jj < 4; ++jj)
      out[(gr0 + row) * HID + jl + jj * 32] = emb[jj] * inv[row];
  }
}

// ---------------------------------------------------------------------------
extern "C" void kernel_launch(void* const* d_in, const int* in_sizes, int n_in,
                              void* d_out, int out_size, void* d_ws, size_t ws_size,
                              hipStream_t stream) {
  const float* a    = (const float*)d_in[0];
  const float* p    = (const float*)d_in[1];
  const float* nn   = (const float*)d_in[2];
  const float* Wih1 = (const float*)d_in[3];
  const float* Whh1 = (const float*)d_in[4];
  const float* bih1 = (const float*)d_in[5];
  const float* bhh1 = (const float*)d_in[6];
  const float* g1   = (const float*)d_in[7];
  const float* b1   = (const float*)d_in[8];
  const float* Wih2 = (const float*)d_in[9];
  const float* Whh2 = (const float*)d_in[10];
  const float* bih2 = (const float*)d_in[11];
  const float* bhh2 = (const float*)d_in[12];
  const float* g2   = (const float*)d_in[13];
  const float* b2   = (const float*)d_in[14];
  const float* fcW  = (const float*)d_in[15];
  const float* fcb  = (const float*)d_in[16];

  char* ws = (char*)d_ws;
  float* stats    = (float*)(ws + 0);         // 1536 f32: s1sum,s1sq,s2sum,s2sq
  float* b1c      = (float*)(ws + 6144);      // 512 f32
  float* bias2eff = (float*)(ws + 8192);      // 1536 f32
  _Float16* whhT1 = (_Float16*)(ws + 14336);    // 131072B
  _Float16* whhT2 = (_Float16*)(ws + 145408);   // 131072B
  _Float16* w2s   = (_Float16*)(ws + 276480);   // 393216B
  _Float16* hlast = (_Float16*)(ws + 669696);   // 393216B
  _Float16* xpad  = (_Float16*)(ws + 1062912);  // 3145728B
  _Float16* hs1   = (_Float16*)(ws + 4208640);  // 50331648B -> ends @54540288
  unsigned* bar   = (unsigned*)(ws + 54540288); // 4B barrier counter

  hipMemsetAsync(bar, 0, 4, stream);           // barrier counter = 0

  mega_kernel<<<96, 512, 0, stream>>>(
      a, p, nn, Wih1, Whh1, bih1, bhh1, g1, b1,
      Wih2, Whh2, bih2, bhh2, g2, b2, fcW, fcb,
      (float*)d_out, stats, b1c, bias2eff,
      whhT1, whhT2, w2s, hlast, xpad, hs1, bar);
}